// Round 1
// baseline (77.702 us; speedup 1.0000x reference)
//
#include <hip/hip_runtime.h>

// Graph_Learn: out[n,i,j] = exp(sum_f a_f*|x[n,2,i,f]-x[n,2,j,f]|) / denom
// N=64, T=5, V=64, F=256.  Output (64,64,64) fp32.
//
// Facts exploited:
//  - a >= 0  =>  a*|xi-xj| = |a*xi - a*xj|  => prescale x by a*log2(e) once
//    (kernel 1), making the inner loop pure sub+abs-add and exp -> exp2.
//  - S symmetric (bitwise) => reference column-sum denom == row sum, so each
//    wave owning complete rows normalizes via a 64-lane shuffle reduction.
// Decomposition: 256 blocks (n x 4 row-tiles), 4 waves/block, 4 rows/wave,
// lane = j. xj from LDS (xor-swizzled, conflict-free b128), xi rows via
// wave-uniform loads (intended to be s_load on the SMEM pipe).

#define NN 64
#define TT 5
#define VV 64
#define FF 256
#define TMID 2

// Kernel 1: y[n][j][f] = x[n][TMID][j][f] * a[f] * log2(e)
__global__ void prescale_k(const float* __restrict__ x, const float* __restrict__ a,
                           float* __restrict__ y, int ynstride4) {
    int idx = blockIdx.x * 256 + threadIdx.x;   // float4 units, 0..262143
    int f4 = idx & 63;
    int j  = (idx >> 6) & 63;
    int n  = idx >> 12;
    const float4* xs = (const float4*)x;
    const float4* av = (const float4*)a;
    size_t src = ((size_t)(n * TT + TMID) * VV + j) * (FF / 4) + f4;
    float4 xv = xs[src];
    float4 s  = av[f4];
    const float L2E = 1.4426950408889634f;
    float4 o;
    o.x = xv.x * (s.x * L2E);
    o.y = xv.y * (s.y * L2E);
    o.z = xv.z * (s.z * L2E);
    o.w = xv.w * (s.w * L2E);
    ((float4*)y)[(size_t)n * ynstride4 + (j * (FF / 4)) + f4] = o;
}

// Kernel 2: per block (iq, n): rows i0..i0+15; per wave 4 rows; lane = j.
__global__ __launch_bounds__(256) void pairnorm_k(const float* __restrict__ y,
                                                  float* __restrict__ out,
                                                  int ynstride4) {
    __shared__ float4 slab[VV * 64];   // 64 rows x 64 float4-chunks, xor-swizzled = 64 KB

    const int tid  = threadIdx.x;
    const int lane = tid & 63;
    const int w    = tid >> 6;
    const int iq   = blockIdx.x;   // 0..3
    const int n    = blockIdx.y;   // 0..63

    const float4* ybase = (const float4*)y + (size_t)n * ynstride4;

    // Stage the prescaled 64x256 slab into LDS. chunk (j,c) stored at
    // j*64 + (c ^ (j&7)) -> both the stage stores and the compute reads are
    // conflict-free (every 8-lane phase covers all 32 banks).
    #pragma unroll
    for (int it = 0; it < 16; ++it) {
        int chunk = it * 256 + tid;
        int j = chunk >> 6;
        int c = chunk & 63;
        slab[(j << 6) + (c ^ (j & 7))] = ybase[chunk];
    }
    __syncthreads();

    const int i0 = __builtin_amdgcn_readfirstlane((iq << 4) + (w << 2));
    const float4* yi = ybase + (i0 << 6);   // wave-uniform row pointers -> s_load

    float acc0 = 0.f, acc1 = 0.f, acc2 = 0.f, acc3 = 0.f;
    const int rb = lane << 6;
    const int s7 = lane & 7;

    #pragma unroll 4
    for (int c = 0; c < 64; ++c) {
        float4 xj = slab[rb + (c ^ s7)];
        float4 r0 = yi[c];
        float4 r1 = yi[64 + c];
        float4 r2 = yi[128 + c];
        float4 r3 = yi[192 + c];
        acc0 += (fabsf(r0.x - xj.x) + fabsf(r0.y - xj.y)) +
                (fabsf(r0.z - xj.z) + fabsf(r0.w - xj.w));
        acc1 += (fabsf(r1.x - xj.x) + fabsf(r1.y - xj.y)) +
                (fabsf(r1.z - xj.z) + fabsf(r1.w - xj.w));
        acc2 += (fabsf(r2.x - xj.x) + fabsf(r2.y - xj.y)) +
                (fabsf(r2.z - xj.z) + fabsf(r2.w - xj.w));
        acc3 += (fabsf(r3.x - xj.x) + fabsf(r3.y - xj.y)) +
                (fabsf(r3.z - xj.z) + fabsf(r3.w - xj.w));
    }

    // acc already includes log2(e) -> exp2
    float s0 = exp2f(acc0), s1 = exp2f(acc1), s2 = exp2f(acc2), s3 = exp2f(acc3);

    // row sums across the 64 lanes (= full row; symmetric => matches reference denom)
    float d0 = s0, d1 = s1, d2 = s2, d3 = s3;
    #pragma unroll
    for (int m = 1; m < 64; m <<= 1) {
        d0 += __shfl_xor(d0, m, 64);
        d1 += __shfl_xor(d1, m, 64);
        d2 += __shfl_xor(d2, m, 64);
        d3 += __shfl_xor(d3, m, 64);
    }

    float* op = out + ((size_t)n * VV + i0) * VV + lane;
    op[0 * VV] = s0 / d0;
    op[1 * VV] = s1 / d1;
    op[2 * VV] = s2 / d2;
    op[3 * VV] = s3 / d3;
}

extern "C" void kernel_launch(void* const* d_in, const int* in_sizes, int n_in,
                              void* d_out, int out_size, void* d_ws, size_t ws_size,
                              hipStream_t stream) {
    const float* x = (const float*)d_in[0];
    const float* a = (const float*)d_in[1];
    float* out = (float*)d_out;

    const size_t y_bytes = (size_t)NN * VV * FF * sizeof(float);   // 4 MB
    float* y;
    int ystr4;
    if (ws_size >= y_bytes) {
        y = (float*)d_ws;
        ystr4 = VV * FF / 4;          // packed [n][64][256]
    } else {
        // fallback scratch: the unused t=0 slice of x (harness restores d_in
        // from pristine before every launch; we write then read in-launch).
        y = (float*)d_in[0];
        ystr4 = TT * VV * FF / 4;     // n-stride of x, t=0 offset is 0
    }

    hipLaunchKernelGGL(prescale_k, dim3(1024), dim3(256), 0, stream, x, a, y, ystr4);
    hipLaunchKernelGGL(pairnorm_k, dim3(4, 64), dim3(256), 0, stream, y, out, ystr4);
}

// Round 2
// 75.560 us; speedup vs baseline: 1.0283x; 1.0283x over previous
//
#include <hip/hip_runtime.h>

// Graph_Learn: out[n,i,j] = exp(sum_f a_f*|x[n,2,i,f]-x[n,2,j,f]|) / denom[n,j]
// N=64, T=5, V=64, F=256.  Output (64,64,64) fp32.
//
// Single fused kernel.
//  - a >= 0  =>  a*|xi-xj| = |a*xi - a*xj|  => scale x by a*log2(e) during LDS
//    staging; inner loop is pure v_sub/v_add-with-abs; exp -> exp2.
//  - S bitwise-symmetric => reference col-sum denom == row sum -> 64-lane
//    shuffle reduction, no second pass.
//  - LDS slab xor-swizzled: chunk (j,c) at j*64 + (c^(j&7)).  Conflict-free for
//    (a) staging stores (j wave-uniform, c=lane), (b) per-lane xj reads
//    (row=lane, c uniform), (c) wave-uniform i-row broadcasts.
//  - Grid 512 = 64 n x 8 row-tiles, 256 thr, 2 rows/wave; 64 KB LDS ->
//    2 blocks/CU = 2 waves/SIMD for latency hiding.

#define NN 64
#define TT 5
#define VV 64
#define FF 256
#define TMID 2

__global__ __launch_bounds__(256) void graphlearn_fused_k(const float* __restrict__ x,
                                                          const float* __restrict__ a,
                                                          float* __restrict__ out) {
    __shared__ float4 slab[VV * 64];   // 64 rows x 64 float4 chunks = 64 KB

    const int tid  = threadIdx.x;
    const int lane = tid & 63;
    const int w    = tid >> 6;          // wave 0..3
    const int tile = blockIdx.x;        // 0..7  (8 rows per block)
    const int n    = blockIdx.y;        // 0..63

    // ---- fused prescale + stage: slab[j][c] = x[n,2,j,c]*a[c]*log2e ----
    // staging thread handles c = tid&63 (wave-invariant across iterations)
    const float L2E = 1.4426950408889634f;
    float4 s = ((const float4*)a)[lane];
    s.x *= L2E; s.y *= L2E; s.z *= L2E; s.w *= L2E;

    const float4* xs = (const float4*)x + ((size_t)(n * TT + TMID) * VV) * (FF / 4);
    #pragma unroll
    for (int it = 0; it < 16; ++it) {
        int j = it * 4 + w;             // wave-uniform row
        float4 xv = xs[(j << 6) + lane];
        float4 o;
        o.x = xv.x * s.x; o.y = xv.y * s.y; o.z = xv.z * s.z; o.w = xv.w * s.w;
        slab[(j << 6) + (lane ^ (j & 7))] = o;
    }
    __syncthreads();

    // ---- all-pairs weighted-L1 for rows i0, i0+1; lane = j ----
    const int i0 = __builtin_amdgcn_readfirstlane((tile << 3) + (w << 1));
    const int r0base = (i0 << 6);
    const int r1base = ((i0 + 1) << 6);
    const int x0 = i0 & 7;
    const int x1 = (i0 + 1) & 7;

    float acc0 = 0.f, acc1 = 0.f;
    const int rb = lane << 6;
    const int s7 = lane & 7;

    #pragma unroll 8
    for (int c = 0; c < 64; ++c) {
        float4 xj = slab[rb + (c ^ s7)];
        float4 r0 = slab[r0base + (c ^ x0)];   // wave-uniform -> LDS broadcast
        float4 r1 = slab[r1base + (c ^ x1)];
        acc0 += (fabsf(r0.x - xj.x) + fabsf(r0.y - xj.y)) +
                (fabsf(r0.z - xj.z) + fabsf(r0.w - xj.w));
        acc1 += (fabsf(r1.x - xj.x) + fabsf(r1.y - xj.y)) +
                (fabsf(r1.z - xj.z) + fabsf(r1.w - xj.w));
    }

    float s0 = exp2f(acc0), s1 = exp2f(acc1);

    // row sum over 64 lanes (= reference's column denom, by symmetry)
    float d0 = s0, d1 = s1;
    #pragma unroll
    for (int m = 1; m < 64; m <<= 1) {
        d0 += __shfl_xor(d0, m, 64);
        d1 += __shfl_xor(d1, m, 64);
    }

    float* op = out + ((size_t)n * VV + i0) * VV + lane;
    op[0]  = s0 / d0;
    op[VV] = s1 / d1;
}

extern "C" void kernel_launch(void* const* d_in, const int* in_sizes, int n_in,
                              void* d_out, int out_size, void* d_ws, size_t ws_size,
                              hipStream_t stream) {
    const float* x = (const float*)d_in[0];
    const float* a = (const float*)d_in[1];
    float* out = (float*)d_out;
    (void)d_ws; (void)ws_size;

    hipLaunchKernelGGL(graphlearn_fused_k, dim3(8, 64), dim3(256), 0, stream,
                       x, a, out);
}

// Round 3
// 75.264 us; speedup vs baseline: 1.0324x; 1.0039x over previous
//
#include <hip/hip_runtime.h>

// Graph_Learn: out[n,i,j] = exp(sum_f a_f*|x[n,2,i,f]-x[n,2,j,f]|) / denom[n,j]
// N=64, T=5, V=64, F=256.  Output (64,64,64) fp32.
//
// Single fused kernel.
//  - a >= 0  =>  a*|xi-xj| = |a*xi - a*xj|  => scale x by a*log2(e) during LDS
//    staging; inner loop is pure v_sub/v_add-with-abs; exp -> exp2.
//  - S bitwise-symmetric => reference col-sum denom == row sum -> 64-lane
//    shuffle reduction, no second pass.
//  - LDS slab PADDED (row stride 65 float4, not xor-swizzled): every c-loop
//    access is base + c*16B -> ds_read_b128 immediate offsets, ZERO address
//    VALU in the hot loop.  Banks: xj read = (4j+4c) mod 32, conflict-free;
//    i-row reads wave-uniform broadcast; staging stores contiguous.
//  - Grid 512 = 64 n x 8 row-tiles, 256 thr, 2 rows/wave; 65 KB LDS ->
//    2 blocks/CU = 2 waves/SIMD.

#define NN 64
#define TT 5
#define VV 64
#define FF 256
#define TMID 2
#define RSTR 65   // float4 row stride (64 + 1 pad)

__global__ __launch_bounds__(256) void graphlearn_fused_k(const float* __restrict__ x,
                                                          const float* __restrict__ a,
                                                          float* __restrict__ out) {
    __shared__ float4 slab[VV * RSTR];   // 64 rows x 65 float4 = 65 KB

    const int tid  = threadIdx.x;
    const int lane = tid & 63;
    const int w    = tid >> 6;          // wave 0..3
    const int tile = blockIdx.x;        // 0..7  (8 rows per block)
    const int n    = blockIdx.y;        // 0..63

    // ---- fused prescale + stage: slab[j][c] = x[n,2,j,c]*a[c]*log2e ----
    const float L2E = 1.4426950408889634f;
    float4 s = ((const float4*)a)[lane];
    s.x *= L2E; s.y *= L2E; s.z *= L2E; s.w *= L2E;

    const float4* xs = (const float4*)x + ((size_t)(n * TT + TMID) * VV) * (FF / 4);
    #pragma unroll
    for (int it = 0; it < 16; ++it) {
        int j = it * 4 + w;             // wave-uniform row
        float4 xv = xs[(j << 6) + lane];
        float4 o;
        o.x = xv.x * s.x; o.y = xv.y * s.y; o.z = xv.z * s.z; o.w = xv.w * s.w;
        slab[j * RSTR + lane] = o;
    }
    __syncthreads();

    // ---- all-pairs weighted-L1 for rows i0, i0+1; lane = j ----
    const int i0 = __builtin_amdgcn_readfirstlane((tile << 3) + (w << 1));
    const float4* pj = &slab[lane * RSTR];        // per-lane row j
    const float4* pi = &slab[i0 * RSTR];          // wave-uniform rows i0, i0+1

    float acc0 = 0.f, acc1 = 0.f;

    #pragma unroll 8
    for (int c = 0; c < 64; ++c) {
        float4 xj = pj[c];
        float4 r0 = pi[c];                        // broadcast
        float4 r1 = pi[RSTR + c];                 // broadcast (imm offset 1040)
        acc0 += (fabsf(r0.x - xj.x) + fabsf(r0.y - xj.y)) +
                (fabsf(r0.z - xj.z) + fabsf(r0.w - xj.w));
        acc1 += (fabsf(r1.x - xj.x) + fabsf(r1.y - xj.y)) +
                (fabsf(r1.z - xj.z) + fabsf(r1.w - xj.w));
    }

    float s0 = exp2f(acc0), s1 = exp2f(acc1);

    // row sum over 64 lanes (= reference's column denom, by symmetry)
    float d0 = s0, d1 = s1;
    #pragma unroll
    for (int m = 1; m < 64; m <<= 1) {
        d0 += __shfl_xor(d0, m, 64);
        d1 += __shfl_xor(d1, m, 64);
    }

    float* op = out + ((size_t)n * VV + i0) * VV + lane;
    op[0]  = s0 / d0;
    op[VV] = s1 / d1;
}

extern "C" void kernel_launch(void* const* d_in, const int* in_sizes, int n_in,
                              void* d_out, int out_size, void* d_ws, size_t ws_size,
                              hipStream_t stream) {
    const float* x = (const float*)d_in[0];
    const float* a = (const float*)d_in[1];
    float* out = (float*)d_out;
    (void)d_ws; (void)ws_size;

    hipLaunchKernelGGL(graphlearn_fused_k, dim3(8, 64), dim3(256), 0, stream,
                       x, a, out);
}